// Round 5
// baseline (314.724 us; speedup 1.0000x reference)
//
#include <hip/hip_runtime.h>
#include <hip/hip_bf16.h>
#include <cstdint>

#define TPB 256

constexpr int B = 8, C = 684, H = 64, W = 256;
constexpr int HID = 256, A = 512, K = 11;
constexpr int HW = H * W;      // 16384
constexpr int KK = K * K;      // 121
constexpr int KP = 128;        // padded tap count (K-dim for MFMA)

typedef __attribute__((ext_vector_type(8))) short bf16x8;
typedef __attribute__((ext_vector_type(4))) float f32x4;

__device__ __forceinline__ float fast_tanh(float x) {
    // tanh(x) = 1 - 2/(e^{2x}+1); saturates correctly at +/-inf
    float e = __expf(2.f * x);
    return 1.f - 2.f * __builtin_amdgcn_rcpf(e + 1.f);
}

__device__ __forceinline__ unsigned short f2bf(float f) {
    unsigned u = __float_as_uint(f);
    u += 0x7fffu + ((u >> 16) & 1u);   // RNE
    return (unsigned short)(u >> 16);
}

// Fused: query[b,a] = hidden[b,:] @ W_h[:,a] + b_h[a]   (blocks 0..15)
//        fwb[a][t]  = bf16(sum_c conv_w[c,0,t] * W_att[c,a])  (blocks 16..271)
__global__ void prep_kernel(const float* __restrict__ hidden,
                            const float* __restrict__ W_h,
                            const float* __restrict__ b_h,
                            const float* __restrict__ conv_w,
                            const float* __restrict__ W_att,
                            float* __restrict__ query,
                            unsigned short* __restrict__ fwb) {
    const int bx = blockIdx.x;
    if (bx < 16) {
        // query: hidden[b,k] is wave-uniform (s_load); W_h row reads coalesced
        int b = bx >> 1;
        int a = ((bx & 1) << 8) + threadIdx.x;
        float q = b_h[a];
        const float* hb = hidden + b * HID;
        for (int k = 0; k < HID; ++k)
            q = fmaf(hb[k], W_h[k * A + a], q);
        query[b * A + a] = q;
    } else {
        int idx = (bx - 16) * TPB + threadIdx.x;   // A*KP = 65536
        int t = idx >> 9, a = idx & (A - 1);       // t uniform per half-block
        float v = 0.f;
        if (t < KK) {
            for (int ch = 0; ch < 512; ++ch)
                v = fmaf(conv_w[ch * KK + t], W_att[ch * A + a], v);
        }
        fwb[a * KP + t] = f2bf(v);
    }
}

// Implicit-GEMM energy kernel + fused per-row softmax partials.
// Block = (b,h): 256 pixels x 512 a. 8 waves, wave owns 64 a.
// MFMA 16x16x32 bf16: A = fw (a x taps), B = im2col patch (taps x pixels).
// C layout (m89-verified): col = lane&15 = pixel, row = (lane>>4)*4+reg = a-offset.
// VGPR diet: query folded into acc init; W_alpha reloaded per pass (L1);
// no trans prefetch (TLP at 2 blocks/CU hides it). Target <=128 VGPR.
__global__ __launch_bounds__(512, 4) void energy_kernel(
    const float* __restrict__ alpha_sum,
    const float* __restrict__ trans,
    const float* __restrict__ query,
    const unsigned short* __restrict__ fwb,
    const float* __restrict__ W_alpha,
    const float* __restrict__ b_alpha,
    const float* __restrict__ mask,
    float* __restrict__ energy,
    float* __restrict__ pm,
    float* __restrict__ ps) {
    const int h = blockIdx.x, b = blockIdx.y;
    const int tid = threadIdx.x;
    const int lane = tid & 63, wid = tid >> 6;
    const int lg = lane >> 4, lr = lane & 15;   // k-group, row-in-16
    const int aw = wid * 64;                    // wave's a-base

    __shared__ float nb[K][272];                // alpha_sum halo rows
    __shared__ unsigned short patch[16 * KP];   // [p][tap] bf16, XOR-swizzled
    __shared__ float part[8][16];
    __shared__ float erow[256];
    __shared__ float pmw[4], psw[4];

    // stage halo: rows h-5..h+5, cols -5..260
    const float* as_b = alpha_sum + b * HW;
    for (int idx = tid; idx < K * 266; idx += 512) {
        int r = idx / 266, j = idx - r * 266;
        int gh = h + r - 5, gw = j - 5;
        float v = 0.f;
        if (gh >= 0 && gh < H && gw >= 0 && gw < W) v = as_b[gh * W + gw];
        nb[r][j] = v;
    }

    // persistent fw A-frags: fw[aw+s*16+lr][ks*32 + lg*8 .. +7]
    bf16x8 fwf[4][4];
#pragma unroll
    for (int s = 0; s < 4; ++s)
#pragma unroll
        for (int ks = 0; ks < 4; ++ks)
            fwf[s][ks] = *(const bf16x8*)(fwb + (aw + s * 16 + lr) * KP + ks * 32 + lg * 8);

    const float4* q4 = (const float4*)(query + b * A + aw);   // L1-resident
    const float4* w4 = (const float4*)(W_alpha + aw);         // L1-resident
    const float* tb = trans + (size_t)b * A * HW + h * W;
    const float bA = b_alpha[0];
    __syncthreads();

    for (int pass = 0; pass < 16; ++pass) {
        const int p0 = pass * 16;
        // ---- build bf16 im2col patch for pixels p0..p0+15 (4 entries/thread) ----
        {
            const int i0 = tid * 4;
            const int p = i0 >> 7;          // 0..15
            const int tap = i0 & 127;       // multiple of 4
            unsigned short e[4];
#pragma unroll
            for (int j = 0; j < 4; ++j) {
                int t = tap + j;
                float v = 0.f;
                if (t < KK) {
                    int r = t / K, c = t - r * K;
                    v = nb[r][p0 + p + c];
                }
                e[j] = f2bf(v);
            }
            uint2 pk;
            pk.x = (unsigned)e[0] | ((unsigned)e[1] << 16);
            pk.y = (unsigned)e[2] | ((unsigned)e[3] << 16);
            int idx = (p * KP + tap) ^ ((p & 7) << 3);   // ushort units; byte ^= (p&7)<<4
            *(uint2*)&patch[idx] = pk;
        }
        __syncthreads();

        // trans loads for this pass (issued before MFMA; consumed in epilogue)
        float tc[4][4];
#pragma unroll
        for (int s = 0; s < 4; ++s)
#pragma unroll
            for (int j = 0; j < 4; ++j)
                tc[s][j] = tb[(size_t)(aw + s * 16 + lg * 4 + j) * HW + p0 + lr];

        // ---- K-loop: 4 k-steps x 4 a-subtiles; acc starts at query ----
        f32x4 acc[4];
#pragma unroll
        for (int s = 0; s < 4; ++s) {
            float4 qv = q4[s * 4 + lg];
            acc[s] = (f32x4){qv.x, qv.y, qv.z, qv.w};
        }
#pragma unroll
        for (int ks = 0; ks < 4; ++ks) {
            int idx = (lr * KP + ks * 32 + lg * 8) ^ ((lr & 7) << 3);
            bf16x8 pf = *(const bf16x8*)&patch[idx];
#pragma unroll
            for (int s = 0; s < 4; ++s)
                acc[s] = __builtin_amdgcn_mfma_f32_16x16x32_bf16(fwf[s][ks], pf, acc[s], 0, 0, 0);
        }

        // ---- fused epilogue: tanh(cov + q + trans) * w_alpha, reduce over a ----
        float es = 0.f;
#pragma unroll
        for (int s = 0; s < 4; ++s) {
            float4 wv = w4[s * 4 + lg];
#pragma unroll
            for (int j = 0; j < 4; ++j) {
                float x = acc[s][j] + tc[s][j];
                float wj = (j == 0) ? wv.x : (j == 1) ? wv.y : (j == 2) ? wv.z : wv.w;
                es = fmaf(fast_tanh(x), wj, es);
            }
        }
        // lanes {l, l^16, l^32, l^48} share pixel lr -> reduce over a-groups
        es += __shfl_xor(es, 16, 64);
        es += __shfl_xor(es, 32, 64);
        if (lane < 16) part[wid][lane] = es;
        __syncthreads();

        if (tid < 16) {
            float e = part[0][tid];
#pragma unroll
            for (int wv = 1; wv < 8; ++wv) e += part[wv][tid];
            e += bA;
            energy[(b * H + h) * W + p0 + tid] = e;
            erow[p0 + tid] = e;
        }
    }

    // ---- fused per-row softmax partial: pm/ps[b*H+h] ----
    __syncthreads();
    if (tid < 256) {
        float v = erow[tid];
        float s = mask[b * HW + h * W + tid];   // exp(v-v)*mk
        float m = v;
#pragma unroll
        for (int off = 1; off < 64; off <<= 1) {
            float m2 = __shfl_xor(m, off, 64);
            float s2 = __shfl_xor(s, off, 64);
            float nm = fmaxf(m, m2);
            s = s * __expf(m - nm) + s2 * __expf(m2 - nm);
            m = nm;
        }
        if ((tid & 63) == 0) { pmw[tid >> 6] = m; psw[tid >> 6] = s; }
    }
    __syncthreads();
    if (tid == 0) {
        float m = pmw[0], s = psw[0];
#pragma unroll
        for (int i = 1; i < 4; ++i) {
            float m2 = pmw[i], s2 = psw[i];
            float nm = fmaxf(m, m2);
            s = s * __expf(m - nm) + s2 * __expf(m2 - nm);
            m = nm;
        }
        pm[b * H + h] = m;
        ps[b * H + h] = s;
    }
}

// Fused alpha + context.
// Block (c,b): combines pm/ps -> smax,sinv; computes al inline; dots with feat.
// Block c==0 additionally writes out_alpha / out_nas.
__global__ void context_kernel(const float* __restrict__ feat,
                               const float* __restrict__ energy,
                               const float* __restrict__ mask,
                               const float* __restrict__ alpha_sum,
                               const float* __restrict__ pm,
                               const float* __restrict__ ps,
                               float* __restrict__ out_ctx,
                               float* __restrict__ out_alpha,
                               float* __restrict__ out_nas) {
    const int c = blockIdx.x, b = blockIdx.y;
    __shared__ float smax, sinv;
    if (threadIdx.x < 64) {
        float m = pm[b * H + threadIdx.x];
        float s = ps[b * H + threadIdx.x];
#pragma unroll
        for (int off = 32; off > 0; off >>= 1) {
            float m2 = __shfl_xor(m, off, 64);
            float s2 = __shfl_xor(s, off, 64);
            float nm = fmaxf(m, m2);
            s = s * __expf(m - nm) + s2 * __expf(m2 - nm);
            m = nm;
        }
        if (threadIdx.x == 0) { smax = m; sinv = 1.f / (s + 1e-10f); }
    }
    __syncthreads();
    const float mx = smax, iv = sinv;

    const float4* f4 = (const float4*)(feat + ((size_t)b * C + c) * HW);
    const float4* e4 = (const float4*)(energy + b * HW);
    const float4* m4 = (const float4*)(mask + b * HW);
    const bool wr_out = (c == 0);
    float s = 0.f;
    for (int i = threadIdx.x; i < HW / 4; i += TPB) {
        float4 fv = f4[i];
        float4 ev = e4[i];
        float4 mv = m4[i];
        float4 al;
        al.x = __expf(ev.x - mx) * mv.x * iv;
        al.y = __expf(ev.y - mx) * mv.y * iv;
        al.z = __expf(ev.z - mx) * mv.z * iv;
        al.w = __expf(ev.w - mx) * mv.w * iv;
        float4 am;
        am.x = (al.x > 0.02f) ? al.x : 0.f;
        am.y = (al.y > 0.02f) ? al.y : 0.f;
        am.z = (al.z > 0.02f) ? al.z : 0.f;
        am.w = (al.w > 0.02f) ? al.w : 0.f;
        s += fv.x * am.x + fv.y * am.y + fv.z * am.z + fv.w * am.w;
        if (wr_out) {
            ((float4*)out_alpha)[b * HW / 4 + i] = al;
            float4 asv = ((const float4*)alpha_sum)[b * HW / 4 + i];
            float4 nv;
            nv.x = al.x + asv.x; nv.y = al.y + asv.y;
            nv.z = al.z + asv.z; nv.w = al.w + asv.w;
            ((float4*)out_nas)[b * HW / 4 + i] = nv;
        }
    }
    for (int off = 32; off > 0; off >>= 1) s += __shfl_down(s, off, 64);
    __shared__ float ls[TPB / 64];
    int lane = threadIdx.x & 63, wid = threadIdx.x >> 6;
    if (lane == 0) ls[wid] = s;
    __syncthreads();
    if (threadIdx.x == 0) {
        float t = 0.f;
        for (int i = 0; i < TPB / 64; ++i) t += ls[i];
        out_ctx[b * C + c] = t;
    }
}

extern "C" void kernel_launch(void* const* d_in, const int* in_sizes, int n_in,
                              void* d_out, int out_size, void* d_ws, size_t ws_size,
                              hipStream_t stream) {
    const float* cnn_features = (const float*)d_in[0];
    const float* trans        = (const float*)d_in[1];
    const float* hidden       = (const float*)d_in[2];
    const float* alpha_sum    = (const float*)d_in[3];
    const float* image_mask   = (const float*)d_in[4];
    const float* W_h          = (const float*)d_in[5];
    const float* b_h          = (const float*)d_in[6];
    const float* conv_w       = (const float*)d_in[7];
    const float* W_att        = (const float*)d_in[8];
    const float* W_alpha      = (const float*)d_in[9];
    const float* b_alpha      = (const float*)d_in[10];

    float* out       = (float*)d_out;
    float* out_ctx   = out;               // B*C
    float* out_alpha = out + B * C;       // B*HW
    float* out_nas   = out_alpha + B * HW;

    float* ws = (float*)d_ws;
    float*          query  = ws;                           // 4096 f
    unsigned short* fwb    = (unsigned short*)(ws + 4096); // 65536 ushort = 32768 f
    float*          energy = ws + 4096 + 32768;            // 131072 f
    float*          pm     = energy + B * HW;              // 512
    float*          ps     = pm + B * H;                   // 512

    hipLaunchKernelGGL(prep_kernel, dim3(16 + (A * KP) / TPB), dim3(TPB), 0, stream,
                       hidden, W_h, b_h, conv_w, W_att, query, fwb);
    hipLaunchKernelGGL(energy_kernel, dim3(H, B), dim3(512), 0, stream,
                       alpha_sum, trans, query, fwb, W_alpha, b_alpha, image_mask,
                       energy, pm, ps);
    hipLaunchKernelGGL(context_kernel, dim3(C, B), dim3(TPB), 0, stream,
                       cnn_features, energy, image_mask, alpha_sum, pm, ps,
                       out_ctx, out_alpha, out_nas);
}

// Round 6
// 129.235 us; speedup vs baseline: 2.4353x; 2.4353x over previous
//
#include <hip/hip_runtime.h>
#include <hip/hip_bf16.h>
#include <cstdint>

#define TPB 256

constexpr int B = 8, C = 684, H = 64, W = 256;
constexpr int HID = 256, A = 512, K = 11;
constexpr int HW = H * W;      // 16384
constexpr int KK = K * K;      // 121
constexpr int KP = 128;        // padded tap count (K-dim for MFMA)

typedef __attribute__((ext_vector_type(8))) short bf16x8;
typedef __attribute__((ext_vector_type(4))) float f32x4;

__device__ __forceinline__ float fast_tanh(float x) {
    // tanh(x) = 1 - 2/(e^{2x}+1); saturates correctly at +/-inf
    float e = __expf(2.f * x);
    return 1.f - 2.f * __builtin_amdgcn_rcpf(e + 1.f);
}

__device__ __forceinline__ unsigned short f2bf(float f) {
    unsigned u = __float_as_uint(f);
    u += 0x7fffu + ((u >> 16) & 1u);   // RNE
    return (unsigned short)(u >> 16);
}

// Fused: query (blocks 0..15), fw (blocks 16..271), gather-count zeroing (block 0)
__global__ void prep_kernel(const float* __restrict__ hidden,
                            const float* __restrict__ W_h,
                            const float* __restrict__ b_h,
                            const float* __restrict__ conv_w,
                            const float* __restrict__ W_att,
                            float* __restrict__ query,
                            unsigned short* __restrict__ fwb,
                            int* __restrict__ cnt) {
    const int bx = blockIdx.x;
    if (bx == 0 && threadIdx.x < B) cnt[threadIdx.x] = 0;   // reset gather counters
    if (bx < 16) {
        // query: hidden[b,k] wave-uniform (s_load); W_h row reads coalesced
        int b = bx >> 1;
        int a = ((bx & 1) << 8) + threadIdx.x;
        float q = b_h[a];
        const float* hb = hidden + b * HID;
        for (int k = 0; k < HID; ++k)
            q = fmaf(hb[k], W_h[k * A + a], q);
        query[b * A + a] = q;
    } else {
        int idx = (bx - 16) * TPB + threadIdx.x;   // A*KP = 65536
        int t = idx >> 9, a = idx & (A - 1);       // t uniform per half-block
        float v = 0.f;
        if (t < KK) {
            for (int ch = 0; ch < 512; ++ch)
                v = fmaf(conv_w[ch * KK + t], W_att[ch * A + a], v);
        }
        fwb[a * KP + t] = f2bf(v);
    }
}

// Implicit-GEMM energy kernel + fused per-row softmax partials.
// Block = (b,h): 256 pixels x 512 a. 8 waves, wave owns 64 a.
// MFMA 16x16x32 bf16: A = fw (a x taps), B = im2col patch (taps x pixels).
// C layout (m89-verified): col = lane&15 = pixel, row = (lane>>4)*4+reg = a-offset.
// NOTE: 2nd launch_bounds arg behaves as blocks/CU on this toolchain
// (measured: (512,4) -> 64-VGPR clamp -> spill disaster). (512,2) = 128 cap.
__global__ __launch_bounds__(512, 2) void energy_kernel(
    const float* __restrict__ alpha_sum,
    const float* __restrict__ trans,
    const float* __restrict__ query,
    const unsigned short* __restrict__ fwb,
    const float* __restrict__ W_alpha,
    const float* __restrict__ b_alpha,
    const float* __restrict__ mask,
    float* __restrict__ energy,
    float* __restrict__ pm,
    float* __restrict__ ps) {
    const int h = blockIdx.x, b = blockIdx.y;
    const int tid = threadIdx.x;
    const int lane = tid & 63, wid = tid >> 6;
    const int lg = lane >> 4, lr = lane & 15;   // k-group, row-in-16
    const int aw = wid * 64;                    // wave's a-base

    __shared__ float nb[K][272];                // alpha_sum halo rows
    __shared__ unsigned short patch[16 * KP];   // [p][tap] bf16, XOR-swizzled
    __shared__ float part[8][16];
    __shared__ float erow[256];
    __shared__ float pmw[4], psw[4];

    // stage halo: rows h-5..h+5, cols -5..260
    const float* as_b = alpha_sum + b * HW;
    for (int idx = tid; idx < K * 266; idx += 512) {
        int r = idx / 266, j = idx - r * 266;
        int gh = h + r - 5, gw = j - 5;
        float v = 0.f;
        if (gh >= 0 && gh < H && gw >= 0 && gw < W) v = as_b[gh * W + gw];
        nb[r][j] = v;
    }

    // persistent fw A-frags: fw[aw+s*16+lr][ks*32 + lg*8 .. +7]
    bf16x8 fwf[4][4];
#pragma unroll
    for (int s = 0; s < 4; ++s)
#pragma unroll
        for (int ks = 0; ks < 4; ++ks)
            fwf[s][ks] = *(const bf16x8*)(fwb + (aw + s * 16 + lr) * KP + ks * 32 + lg * 8);

    const float4* q4 = (const float4*)(query + b * A + aw);   // L1-resident
    const float4* w4 = (const float4*)(W_alpha + aw);         // L1-resident
    const float* tb = trans + (size_t)b * A * HW + h * W;
    const float bA = b_alpha[0];
    __syncthreads();

    for (int pass = 0; pass < 16; ++pass) {
        const int p0 = pass * 16;
        // ---- build bf16 im2col patch for pixels p0..p0+15 (4 entries/thread) ----
        {
            const int i0 = tid * 4;
            const int p = i0 >> 7;          // 0..15
            const int tap = i0 & 127;       // multiple of 4
            unsigned short e[4];
#pragma unroll
            for (int j = 0; j < 4; ++j) {
                int t = tap + j;
                float v = 0.f;
                if (t < KK) {
                    int r = t / K, c = t - r * K;
                    v = nb[r][p0 + p + c];
                }
                e[j] = f2bf(v);
            }
            uint2 pk;
            pk.x = (unsigned)e[0] | ((unsigned)e[1] << 16);
            pk.y = (unsigned)e[2] | ((unsigned)e[3] << 16);
            int idx = (p * KP + tap) ^ ((p & 7) << 3);   // ushort units; byte ^= (p&7)<<4
            *(uint2*)&patch[idx] = pk;
        }
        __syncthreads();

        // trans loads for this pass (issued before MFMA; consumed in epilogue)
        float tc[4][4];
#pragma unroll
        for (int s = 0; s < 4; ++s)
#pragma unroll
            for (int j = 0; j < 4; ++j)
                tc[s][j] = tb[(size_t)(aw + s * 16 + lg * 4 + j) * HW + p0 + lr];

        // ---- K-loop: 4 k-steps x 4 a-subtiles; acc starts at query ----
        f32x4 acc[4];
#pragma unroll
        for (int s = 0; s < 4; ++s) {
            float4 qv = q4[s * 4 + lg];
            acc[s] = (f32x4){qv.x, qv.y, qv.z, qv.w};
        }
#pragma unroll
        for (int ks = 0; ks < 4; ++ks) {
            int idx = (lr * KP + ks * 32 + lg * 8) ^ ((lr & 7) << 3);
            bf16x8 pf = *(const bf16x8*)&patch[idx];
#pragma unroll
            for (int s = 0; s < 4; ++s)
                acc[s] = __builtin_amdgcn_mfma_f32_16x16x32_bf16(fwf[s][ks], pf, acc[s], 0, 0, 0);
        }

        // ---- fused epilogue: tanh(cov + q + trans) * w_alpha, reduce over a ----
        float es = 0.f;
#pragma unroll
        for (int s = 0; s < 4; ++s) {
            float4 wv = w4[s * 4 + lg];
#pragma unroll
            for (int j = 0; j < 4; ++j) {
                float x = acc[s][j] + tc[s][j];
                float wj = (j == 0) ? wv.x : (j == 1) ? wv.y : (j == 2) ? wv.z : wv.w;
                es = fmaf(fast_tanh(x), wj, es);
            }
        }
        // lanes {l, l^16, l^32, l^48} share pixel lr -> reduce over a-groups
        es += __shfl_xor(es, 16, 64);
        es += __shfl_xor(es, 32, 64);
        if (lane < 16) part[wid][lane] = es;
        __syncthreads();

        if (tid < 16) {
            float e = part[0][tid];
#pragma unroll
            for (int wv = 1; wv < 8; ++wv) e += part[wv][tid];
            e += bA;
            energy[(b * H + h) * W + p0 + tid] = e;
            erow[p0 + tid] = e;
        }
    }

    // ---- fused per-row softmax partial: pm/ps[b*H+h] ----
    __syncthreads();
    if (tid < 256) {
        float v = erow[tid];
        float s = mask[b * HW + h * W + tid];   // exp(v-v)*mk
        float m = v;
#pragma unroll
        for (int off = 1; off < 64; off <<= 1) {
            float m2 = __shfl_xor(m, off, 64);
            float s2 = __shfl_xor(s, off, 64);
            float nm = fmaxf(m, m2);
            s = s * __expf(m - nm) + s2 * __expf(m2 - nm);
            m = nm;
        }
        if ((tid & 63) == 0) { pmw[tid >> 6] = m; psw[tid >> 6] = s; }
    }
    __syncthreads();
    if (tid == 0) {
        float m = pmw[0], s = psw[0];
#pragma unroll
        for (int i = 1; i < 4; ++i) {
            float m2 = pmw[i], s2 = psw[i];
            float nm = fmaxf(m, m2);
            s = s * __expf(m - nm) + s2 * __expf(m2 - nm);
            m = nm;
        }
        pm[b * H + h] = m;
        ps[b * H + h] = s;
    }
}

// alpha + new_alpha_sum + sparse gather of (alpha > 0.02) pixels.
// Grid: B*HW/(TPB*4) blocks, float4 per thread; b uniform per block.
__global__ void alpha_kernel(const float* __restrict__ energy,
                             const float* __restrict__ mask,
                             const float* __restrict__ alpha_sum,
                             const float* __restrict__ pm,
                             const float* __restrict__ ps,
                             float* __restrict__ out_alpha,
                             float* __restrict__ out_nas,
                             int* __restrict__ cnt,
                             int* __restrict__ gidx,
                             float* __restrict__ gval) {
    const int i4 = blockIdx.x * TPB + threadIdx.x;   // float4 index, B*HW/4 total
    const int b = i4 >> 12;                          // uniform per block (4096 f4/batch)
    __shared__ float smax, sinv;
    if (threadIdx.x < 64) {
        float m = pm[b * H + threadIdx.x];
        float s = ps[b * H + threadIdx.x];
#pragma unroll
        for (int off = 32; off > 0; off >>= 1) {
            float m2 = __shfl_xor(m, off, 64);
            float s2 = __shfl_xor(s, off, 64);
            float nm = fmaxf(m, m2);
            s = s * __expf(m - nm) + s2 * __expf(m2 - nm);
            m = nm;
        }
        if (threadIdx.x == 0) { smax = m; sinv = 1.f / (s + 1e-10f); }
    }
    __syncthreads();
    const float mx = smax, iv = sinv;

    float4 ev = ((const float4*)energy)[i4];
    float4 mv = ((const float4*)mask)[i4];
    float4 asv = ((const float4*)alpha_sum)[i4];
    float4 al;
    al.x = __expf(ev.x - mx) * mv.x * iv;
    al.y = __expf(ev.y - mx) * mv.y * iv;
    al.z = __expf(ev.z - mx) * mv.z * iv;
    al.w = __expf(ev.w - mx) * mv.w * iv;
    ((float4*)out_alpha)[i4] = al;
    float4 nv;
    nv.x = al.x + asv.x; nv.y = al.y + asv.y;
    nv.z = al.z + asv.z; nv.w = al.w + asv.w;
    ((float4*)out_nas)[i4] = nv;

    // sparse gather (expected: ~0 passing pixels for softmax over 16K)
    const int p0 = (i4 << 2) & (HW - 1);
#pragma unroll
    for (int j = 0; j < 4; ++j) {
        float a = (j == 0) ? al.x : (j == 1) ? al.y : (j == 2) ? al.z : al.w;
        if (a > 0.02f) {
            int slot = atomicAdd(&cnt[b], 1);
            gidx[b * HW + slot] = p0 + j;
            gval[b * HW + slot] = a;
        }
    }
}

// context[b,c] = sum over gathered pixels: gval * feat[b,c,gidx]
__global__ void context_kernel(const float* __restrict__ feat,
                               const int* __restrict__ cnt,
                               const int* __restrict__ gidx,
                               const float* __restrict__ gval,
                               float* __restrict__ out_ctx) {
    const int c = blockIdx.x, b = blockIdx.y;
    const int n = cnt[b];
    const float* fb = feat + ((size_t)b * C + c) * HW;
    float s = 0.f;
    for (int k = threadIdx.x; k < n; k += 64)
        s += gval[b * HW + k] * fb[gidx[b * HW + k]];
#pragma unroll
    for (int off = 32; off > 0; off >>= 1) s += __shfl_down(s, off, 64);
    if (threadIdx.x == 0) out_ctx[b * C + c] = s;
}

extern "C" void kernel_launch(void* const* d_in, const int* in_sizes, int n_in,
                              void* d_out, int out_size, void* d_ws, size_t ws_size,
                              hipStream_t stream) {
    const float* cnn_features = (const float*)d_in[0];
    const float* trans        = (const float*)d_in[1];
    const float* hidden       = (const float*)d_in[2];
    const float* alpha_sum    = (const float*)d_in[3];
    const float* image_mask   = (const float*)d_in[4];
    const float* W_h          = (const float*)d_in[5];
    const float* b_h          = (const float*)d_in[6];
    const float* conv_w       = (const float*)d_in[7];
    const float* W_att        = (const float*)d_in[8];
    const float* W_alpha      = (const float*)d_in[9];
    const float* b_alpha      = (const float*)d_in[10];

    float* out       = (float*)d_out;
    float* out_ctx   = out;               // B*C
    float* out_alpha = out + B * C;       // B*HW
    float* out_nas   = out_alpha + B * HW;

    float* ws = (float*)d_ws;
    float*          query  = ws;                           // 4096 f
    unsigned short* fwb    = (unsigned short*)(ws + 4096); // 65536 ushort = 32768 f
    float*          energy = ws + 4096 + 32768;            // 131072 f
    float*          pm     = energy + B * HW;              // 512
    float*          ps     = pm + B * H;                   // 512
    int*            cnt    = (int*)(ps + B * H);           // 8
    int*            gidx   = cnt + 8;                      // B*HW
    float*          gval   = (float*)(gidx + B * HW);      // B*HW

    hipLaunchKernelGGL(prep_kernel, dim3(16 + (A * KP) / TPB), dim3(TPB), 0, stream,
                       hidden, W_h, b_h, conv_w, W_att, query, fwb, cnt);
    hipLaunchKernelGGL(energy_kernel, dim3(H, B), dim3(512), 0, stream,
                       alpha_sum, trans, query, fwb, W_alpha, b_alpha, image_mask,
                       energy, pm, ps);
    hipLaunchKernelGGL(alpha_kernel, dim3(B * HW / (TPB * 4)), dim3(TPB), 0, stream,
                       energy, image_mask, alpha_sum, pm, ps,
                       out_alpha, out_nas, cnt, gidx, gval);
    hipLaunchKernelGGL(context_kernel, dim3(C, B), dim3(64), 0, stream,
                       cnn_features, cnt, gidx, gval, out_ctx);
}